// Round 2
// baseline (296.625 us; speedup 1.0000x reference)
//
#include <hip/hip_runtime.h>

typedef __bf16 bf16x8 __attribute__((ext_vector_type(8)));
typedef __bf16 bf16x4 __attribute__((ext_vector_type(4)));
typedef float f32x4 __attribute__((ext_vector_type(4)));

#define EPS 1e-5f
#define TPB_TILES 4

// Precompute (re-runs every launch; d_ws is re-poisoned each time):
//   mt[s][c]  = alpha * M[c][s],  M = W_col @ W_row^T   (bf16, [32][32])
//   bwt[g][c][b] = bw[g][b][c]                          (bf16, [64][16][16])
__global__ __launch_bounds__(256) void hbsl_precompute(
    const float* __restrict__ bw, const float* __restrict__ W_row,
    const float* __restrict__ W_col, const float* __restrict__ alpha_p,
    __bf16* __restrict__ mt, __bf16* __restrict__ bwt)
{
    const int t = threadIdx.x;
    if (blockIdx.x == 0) {
        const float alpha = alpha_p[0];
        #pragma unroll
        for (int k = 0; k < 4; ++k) {
            int flat = t + 256 * k;
            int s = flat >> 5, c = flat & 31;
            float acc = 0.f;
            #pragma unroll 8
            for (int kk = 0; kk < 32; ++kk)
                acc += W_col[c * 32 + kk] * W_row[s * 32 + kk];
            mt[s * 32 + c] = (__bf16)(alpha * acc);
        }
    } else {
        int g = blockIdx.x - 1;
        int c = t >> 4, b = t & 15;
        bwt[g * 256 + c * 16 + b] = (__bf16)bw[g * 256 + b * 16 + c];
    }
}

// 512 threads = 8 waves, persistent over TPB_TILES row-tiles of 16 rows each.
// Pipeline per tile: LN (wave-per-row, 2 rows/wave) -> B1 -> prefetch next
// tile's x into regs (in flight across MFMA; vmcnt drain lands at B2, after
// the latency is covered) -> MFMA from LDS/regs only -> B2.
// MFMA: wave wv owns out-tiles [8wv, 8wv+8); block-diag A via zero-inject
// regs (bwf[4]); bias staged in LDS and ridden as the MFMA C operand.
__global__ __launch_bounds__(512, 4) void hbsl_main(
    const float* __restrict__ x, const float* __restrict__ gamma,
    const float* __restrict__ beta, const float* __restrict__ bias,
    const __bf16* __restrict__ mt, const __bf16* __restrict__ bwt,
    float* __restrict__ out)
{
    __shared__ __bf16 xn[16 * 1024];   // XOR-swizzled, exactly 32 KB
    __shared__ float bias_s[1024];
    const int t = threadIdx.x;
    const int lane = t & 63;
    const int wv = t >> 6;                    // 0..7
    const int q = lane >> 4, n = lane & 15;   // MFMA lane decomposition

    // ---- loop-invariant preloads (latency hides under tile-0 x loads) ----
    const bf16x8 mfrag0 = *(const bf16x8*)(mt + n * 32 + q * 8);
    const bf16x8 mfrag1 = *(const bf16x8*)(mt + (16 + n) * 32 + q * 8);
    bf16x8 bwf[4];
    #pragma unroll
    for (int p = 0; p < 4; ++p) {
        const int o0 = wv * 8 + 2 * p;
        const int gp = 31 - (o0 >> 1);
        const int g = (q >= 2) ? (2 * gp + 1) : (2 * gp);  // tile o0 : tile o1
        const int e = (q >= 2) ? (q - 2) * 8 : q * 8;
        bwf[p] = *(const bf16x8*)(bwt + g * 256 + (15 - n) * 16 + e);
    }
    *(float2*)(&bias_s[t * 2]) = *(const float2*)(bias + t * 2);

    bf16x8 bz;
    #pragma unroll
    for (int i = 0; i < 8; ++i) bz[i] = (__bf16)0.f;

    const int r0 = wv * 2, r1 = wv * 2 + 1;       // this wave's two LN rows
    const int wswz0 = (r0 & 7) << 3, wswz1 = (r1 & 7) << 3;
    const int rswz  = (n & 7) << 3;
    const int tile0 = blockIdx.x * TPB_TILES;

    // ---- prologue: issue x loads for tile 0 ----
    float4 va[4], vb[4];
    {
        const float* xr0 = x + (size_t)(tile0 * 16 + r0) * 1024 + lane * 4;
        const float* xr1 = x + (size_t)(tile0 * 16 + r1) * 1024 + lane * 4;
        #pragma unroll
        for (int j = 0; j < 4; ++j) {
            va[j] = *(const float4*)(xr0 + j * 256);
            vb[j] = *(const float4*)(xr1 + j * 256);
        }
    }

    #pragma unroll
    for (int tt = 0; tt < TPB_TILES; ++tt) {
        const int rbase = (tile0 + tt) * 16;

        // ---- LayerNorm: 2 rows per wave, 4 independent reduce chains ----
        float s0 = 0.f, q0 = 0.f, s1 = 0.f, q1 = 0.f;
        #pragma unroll
        for (int j = 0; j < 4; ++j) {
            s0 += va[j].x + va[j].y + va[j].z + va[j].w;
            q0 += va[j].x * va[j].x + va[j].y * va[j].y
                + va[j].z * va[j].z + va[j].w * va[j].w;
            s1 += vb[j].x + vb[j].y + vb[j].z + vb[j].w;
            q1 += vb[j].x * vb[j].x + vb[j].y * vb[j].y
                + vb[j].z * vb[j].z + vb[j].w * vb[j].w;
        }
        #pragma unroll
        for (int m = 1; m < 64; m <<= 1) {
            s0 += __shfl_xor(s0, m, 64);
            q0 += __shfl_xor(q0, m, 64);
            s1 += __shfl_xor(s1, m, 64);
            q1 += __shfl_xor(q1, m, 64);
        }
        const float mu0 = s0 * (1.f / 1024.f);
        const float rs0 = rsqrtf(q0 * (1.f / 1024.f) - mu0 * mu0 + EPS);
        const float mu1 = s1 * (1.f / 1024.f);
        const float rs1 = rsqrtf(q1 * (1.f / 1024.f) - mu1 * mu1 + EPS);
        #pragma unroll
        for (int j = 0; j < 4; ++j) {
            const int col = lane * 4 + j * 256;
            const float4 g4 = *(const float4*)(gamma + col);  // L2-resident
            const float4 b4 = *(const float4*)(beta + col);
            bf16x4 w0, w1;
            w0[0] = (__bf16)((va[j].x - mu0) * rs0 * g4.x + b4.x);
            w0[1] = (__bf16)((va[j].y - mu0) * rs0 * g4.y + b4.y);
            w0[2] = (__bf16)((va[j].z - mu0) * rs0 * g4.z + b4.z);
            w0[3] = (__bf16)((va[j].w - mu0) * rs0 * g4.w + b4.w);
            w1[0] = (__bf16)((vb[j].x - mu1) * rs1 * g4.x + b4.x);
            w1[1] = (__bf16)((vb[j].y - mu1) * rs1 * g4.y + b4.y);
            w1[2] = (__bf16)((vb[j].z - mu1) * rs1 * g4.z + b4.z);
            w1[3] = (__bf16)((vb[j].w - mu1) * rs1 * g4.w + b4.w);
            *(bf16x4*)(&xn[r0 * 1024 + (col ^ wswz0)]) = w0;
            *(bf16x4*)(&xn[r1 * 1024 + (col ^ wswz1)]) = w1;
        }

        __syncthreads();   // B1: xn ready (covers bias_s/preloads on tt==0)

        // ---- prefetch next tile's x; stays in flight across MFMA phase ----
        if (tt + 1 < TPB_TILES) {
            const float* nx0 = x + (size_t)(rbase + 16 + r0) * 1024 + lane * 4;
            const float* nx1 = x + (size_t)(rbase + 16 + r1) * 1024 + lane * 4;
            #pragma unroll
            for (int j = 0; j < 4; ++j) {
                va[j] = *(const float4*)(nx0 + j * 256);
                vb[j] = *(const float4*)(nx1 + j * 256);
            }
        }

        // ---- MFMA + store: LDS/registers only, no global loads ----
        float* orow = out + (size_t)(rbase + n) * 1024;
        #pragma unroll
        for (int p = 0; p < 4; ++p) {
            const int o0 = wv * 8 + 2 * p;    // even out-tile; o1 = o0+1
            const int r  = o0 >> 1;           // monarch window cols [32r,32r+32)
            const int gp = 31 - r;            // block-diag window
            bf16x8 az = *(const bf16x8*)(&xn[n * 1024 + ((r  * 32 + q * 8) ^ rswz)]);
            bf16x8 ay = *(const bf16x8*)(&xn[n * 1024 + ((gp * 32 + q * 8) ^ rswz)]);
            bf16x8 a0 = (q >= 2) ? bwf[p] : bz;   // tile o0: k in [16,32)
            bf16x8 a1 = (q <  2) ? bwf[p] : bz;   // tile o1: k in [0,16)
            f32x4 b0 = *(const f32x4*)(&bias_s[o0 * 16 + q * 4]);
            f32x4 b1 = *(const f32x4*)(&bias_s[o0 * 16 + 16 + q * 4]);
            f32x4 d0 = __builtin_amdgcn_mfma_f32_16x16x32_bf16(mfrag0, az, b0, 0, 0, 0);
            f32x4 d1 = __builtin_amdgcn_mfma_f32_16x16x32_bf16(mfrag1, az, b1, 0, 0, 0);
            d0 = __builtin_amdgcn_mfma_f32_16x16x32_bf16(a0, ay, d0, 0, 0, 0);
            d1 = __builtin_amdgcn_mfma_f32_16x16x32_bf16(a1, ay, d1, 0, 0, 0);
            float* op = orow + o0 * 16 + q * 4;
            *(f32x4*)op        = d0;
            *(f32x4*)(op + 16) = d1;
        }

        if (tt + 1 < TPB_TILES) __syncthreads();   // B2: xn consumed
    }
}

extern "C" void kernel_launch(void* const* d_in, const int* in_sizes, int n_in,
                              void* d_out, int out_size, void* d_ws, size_t ws_size,
                              hipStream_t stream) {
    const float* x      = (const float*)d_in[0];
    const float* gamma  = (const float*)d_in[1];
    const float* beta   = (const float*)d_in[2];
    const float* bw     = (const float*)d_in[3];
    const float* W_row  = (const float*)d_in[4];
    const float* W_col  = (const float*)d_in[5];
    const float* alpha  = (const float*)d_in[6];
    const float* bias   = (const float*)d_in[7];
    float* o = (float*)d_out;

    __bf16* mt  = (__bf16*)d_ws;                       // 32*32*2   = 2048 B
    __bf16* bwt = (__bf16*)((char*)d_ws + 2048);       // 64*256*2  = 32768 B

    const int N = in_sizes[0] / 1024;                  // 32768 rows
    const int n_tiles = N / 16;                        // 2048

    hipLaunchKernelGGL(hbsl_precompute, dim3(65), dim3(256), 0, stream,
                       bw, W_row, W_col, alpha, mt, bwt);
    hipLaunchKernelGGL(hbsl_main, dim3(n_tiles / TPB_TILES), dim3(512), 0, stream,
                       x, gamma, beta, bias, mt, bwt, o);
}

// Round 3
// 257.005 us; speedup vs baseline: 1.1542x; 1.1542x over previous
//
#include <hip/hip_runtime.h>

typedef __bf16 bf16x8 __attribute__((ext_vector_type(8)));
typedef __bf16 bf16x4 __attribute__((ext_vector_type(4)));
typedef float f32x4 __attribute__((ext_vector_type(4)));

#define EPS 1e-5f
#define TILES_PER_BLOCK 8

typedef __attribute__((address_space(3))) unsigned int lds_u32;
typedef const __attribute__((address_space(1))) unsigned int glb_u32;

// Precompute (re-runs every launch; d_ws is re-poisoned each time):
//   mt[s][c]  = alpha * M[c][s],  M = W_col @ W_row^T   (bf16, [32][32])
//   bwt[g][c][b] = bw[g][b][c]                          (bf16, [64][16][16])
__global__ __launch_bounds__(256) void hbsl_precompute(
    const float* __restrict__ bw, const float* __restrict__ W_row,
    const float* __restrict__ W_col, const float* __restrict__ alpha_p,
    __bf16* __restrict__ mt, __bf16* __restrict__ bwt)
{
    const int t = threadIdx.x;
    if (blockIdx.x == 0) {
        const float alpha = alpha_p[0];
        #pragma unroll
        for (int k = 0; k < 4; ++k) {
            int flat = t + 256 * k;
            int s = flat >> 5, c = flat & 31;
            float acc = 0.f;
            #pragma unroll 8
            for (int kk = 0; kk < 32; ++kk)
                acc += W_col[c * 32 + kk] * W_row[s * 32 + kk];
            mt[s * 32 + c] = (__bf16)(alpha * acc);
        }
    } else {
        int g = blockIdx.x - 1;
        int c = t >> 4, b = t & 15;
        bwt[g * 256 + c * 16 + b] = (__bf16)bw[g * 256 + b * 16 + c];
    }
}

// 512 threads = 8 waves, 1 block/CU (135 KB LDS), 8 tiles per block.
// 2-phase DMA pipeline: global_load_lds stages raw fp32 x (pre-swizzled
// source -> 32B-chunk XOR-swizzled LDS layout). Stats+normalize convert the
// wave's private 8KB slab to bf16 xn IN PLACE (writes land linearly because
// the source swizzle and the xn chunk swizzle cancel). DMA for tile t+1 is
// issued after the stats barrier and drains at the MFMA-end barrier, so it
// flies under the whole MFMA+store phase.
__global__ __launch_bounds__(512, 2) void hbsl_main(
    const float* __restrict__ x, const float* __restrict__ gamma,
    const float* __restrict__ beta, const float* __restrict__ bias,
    const __bf16* __restrict__ mt, const __bf16* __restrict__ bwt,
    float* __restrict__ out)
{
    __shared__ float xr[2][16384];     // 2 x 64 KB raw-x / xn double buffer
    __shared__ float bias_s[1024];     // 4 KB
    const int t = threadIdx.x;
    const int lane = t & 63;
    const int wv = t >> 6;                    // 0..7
    const int q = lane >> 4, n = lane & 15;   // MFMA lane decomposition

    // ---- loop-invariant preloads ----
    const bf16x8 mfrag0 = *(const bf16x8*)(mt + n * 32 + q * 8);
    const bf16x8 mfrag1 = *(const bf16x8*)(mt + (16 + n) * 32 + q * 8);
    bf16x8 bwf[4];
    #pragma unroll
    for (int p = 0; p < 4; ++p) {
        const int o0 = wv * 8 + 2 * p;
        const int gb = 31 - (o0 >> 1);
        const int g = (q >= 2) ? (2 * gb + 1) : (2 * gb);  // tile o0 : o1
        const int e = (q >= 2) ? (q - 2) * 8 : q * 8;
        bwf[p] = *(const bf16x8*)(bwt + g * 256 + (15 - n) * 16 + e);
    }
    *(float2*)(&bias_s[t * 2]) = *(const float2*)(bias + t * 2);

    // gamma/beta: per-lane slots are tile-invariant -> persistent registers.
    // Slab rows for this wave: r = 2*wv + (j>>2); source slot D = P ^ E(r),
    // P = (j&3)*64 + lane, E(r) = (r&7)<<1  [16B fp32 slots, 32B-chunk XOR].
    float4 g4[8], b4[8];
    int dofs[8];                        // per-j source float offset in tile
    #pragma unroll
    for (int j = 0; j < 8; ++j) {
        const int r = 2 * wv + (j >> 2);
        const int D = (((j & 3) * 64 + lane) ^ ((r & 7) << 1));
        dofs[j] = r * 1024 + D * 4;
        g4[j] = *(const float4*)(gamma + D * 4);
        b4[j] = *(const float4*)(beta + D * 4);
    }

    bf16x8 bz;
    #pragma unroll
    for (int i = 0; i < 8; ++i) bz[i] = (__bf16)0.f;

    const int nx = n & 7;
    const int nbase = (n >> 1) * 4096 + (n & 1) * 1024;  // xn row base (bf16 elems)

    // ---- prologue: DMA tile 0 into xr[0] ----
    {
        const float* xt = x + (size_t)(blockIdx.x * 16) * 1024;
        #pragma unroll
        for (int k = 0; k < 8; ++k) {
            lds_u32* lp = (lds_u32*)(&xr[0][wv * 2048 + k * 256]);
            __builtin_amdgcn_global_load_lds((glb_u32*)(xt + dofs[k]), lp, 16, 0, 0);
        }
    }
    __syncthreads();   // drains tile-0 DMA; bias_s ready

    for (int tt = 0; tt < TILES_PER_BLOCK; ++tt) {
        const int cur = tt & 1;
        const int tile = blockIdx.x + 256 * tt;      // all blocks sweep together
        const int rbase = tile * 16;
        __bf16* xnb = (__bf16*)(&xr[cur][0]);

        // ---- stats + in-place normalize (wave-private 8 KB slab) ----
        f32x4 xg[8];
        #pragma unroll
        for (int j = 0; j < 8; ++j)
            xg[j] = *(const f32x4*)(&xr[cur][wv * 2048 + j * 256 + lane * 4]);
        float s0 = 0.f, q0 = 0.f, s1 = 0.f, q1 = 0.f;
        #pragma unroll
        for (int j = 0; j < 4; ++j) {
            s0 += xg[j][0] + xg[j][1] + xg[j][2] + xg[j][3];
            q0 += xg[j][0]*xg[j][0] + xg[j][1]*xg[j][1]
                + xg[j][2]*xg[j][2] + xg[j][3]*xg[j][3];
            s1 += xg[j+4][0] + xg[j+4][1] + xg[j+4][2] + xg[j+4][3];
            q1 += xg[j+4][0]*xg[j+4][0] + xg[j+4][1]*xg[j+4][1]
                + xg[j+4][2]*xg[j+4][2] + xg[j+4][3]*xg[j+4][3];
        }
        #pragma unroll
        for (int m = 1; m < 64; m <<= 1) {
            s0 += __shfl_xor(s0, m, 64);
            q0 += __shfl_xor(q0, m, 64);
            s1 += __shfl_xor(s1, m, 64);
            q1 += __shfl_xor(q1, m, 64);
        }
        const float mu0 = s0 * (1.f / 1024.f);
        const float rs0 = rsqrtf(q0 * (1.f / 1024.f) - mu0 * mu0 + EPS);
        const float mu1 = s1 * (1.f / 1024.f);
        const float rs1 = rsqrtf(q1 * (1.f / 1024.f) - mu1 * mu1 + EPS);
        #pragma unroll
        for (int j = 0; j < 8; ++j) {
            const float mu = (j < 4) ? mu0 : mu1;
            const float rs = (j < 4) ? rs0 : rs1;
            bf16x4 w;
            w[0] = (__bf16)((xg[j][0] - mu) * rs * g4[j].x + b4[j].x);
            w[1] = (__bf16)((xg[j][1] - mu) * rs * g4[j].y + b4[j].y);
            w[2] = (__bf16)((xg[j][2] - mu) * rs * g4[j].z + b4[j].z);
            w[3] = (__bf16)((xg[j][3] - mu) * rs * g4[j].w + b4[j].w);
            // swizzles cancel: write lands linearly at slot P within the slab
            const int P = (j & 3) * 64 + lane;
            *(bf16x4*)(&xnb[wv * 4096 + (j >> 2) * 1024 + P * 4]) = w;
        }

        __syncthreads();   // xn visible block-wide (no VM ops pending: free drain)

        // ---- issue next tile's DMA; drains at the loop-end barrier ----
        if (tt + 1 < TILES_PER_BLOCK) {
            const float* xt = x + (size_t)(rbase + 256 * 16) * 1024;
            #pragma unroll
            for (int k = 0; k < 8; ++k) {
                lds_u32* lp = (lds_u32*)(&xr[cur ^ 1][wv * 2048 + k * 256]);
                __builtin_amdgcn_global_load_lds((glb_u32*)(xt + dofs[k]), lp, 16, 0, 0);
            }
        }

        // ---- MFMA + store: LDS/registers only ----
        float* orow = out + (size_t)(rbase + n) * 1024;
        #pragma unroll
        for (int p = 0; p < 4; ++p) {
            const int o0 = wv * 8 + 2 * p;    // even out-tile; o1 = o0+1
            const int rw = o0 >> 1;           // monarch window cols [32rw,+32)
            const int gp = 31 - rw;           // block-diag window
            bf16x8 az = *(const bf16x8*)(&xnb[nbase + ((4 * rw + q) ^ nx) * 8]);
            bf16x8 ay = *(const bf16x8*)(&xnb[nbase + ((4 * gp + q) ^ nx) * 8]);
            bf16x8 a0 = (q >= 2) ? bwf[p] : bz;   // tile o0: k in [16,32)
            bf16x8 a1 = (q <  2) ? bwf[p] : bz;   // tile o1: k in [0,16)
            f32x4 b0 = *(const f32x4*)(&bias_s[o0 * 16 + q * 4]);
            f32x4 b1 = *(const f32x4*)(&bias_s[o0 * 16 + 16 + q * 4]);
            f32x4 d0 = __builtin_amdgcn_mfma_f32_16x16x32_bf16(mfrag0, az, b0, 0, 0, 0);
            f32x4 d1 = __builtin_amdgcn_mfma_f32_16x16x32_bf16(mfrag1, az, b1, 0, 0, 0);
            d0 = __builtin_amdgcn_mfma_f32_16x16x32_bf16(a0, ay, d0, 0, 0, 0);
            d1 = __builtin_amdgcn_mfma_f32_16x16x32_bf16(a1, ay, d1, 0, 0, 0);
            float* op = orow + o0 * 16 + q * 4;
            *(f32x4*)op        = d0;
            *(f32x4*)(op + 16) = d1;
        }

        __syncthreads();   // drains next-tile DMA + this tile's stores
    }
}

extern "C" void kernel_launch(void* const* d_in, const int* in_sizes, int n_in,
                              void* d_out, int out_size, void* d_ws, size_t ws_size,
                              hipStream_t stream) {
    const float* x      = (const float*)d_in[0];
    const float* gamma  = (const float*)d_in[1];
    const float* beta   = (const float*)d_in[2];
    const float* bw     = (const float*)d_in[3];
    const float* W_row  = (const float*)d_in[4];
    const float* W_col  = (const float*)d_in[5];
    const float* alpha  = (const float*)d_in[6];
    const float* bias   = (const float*)d_in[7];
    float* o = (float*)d_out;

    __bf16* mt  = (__bf16*)d_ws;                       // 32*32*2   = 2048 B
    __bf16* bwt = (__bf16*)((char*)d_ws + 2048);       // 64*256*2  = 32768 B

    hipLaunchKernelGGL(hbsl_precompute, dim3(65), dim3(256), 0, stream,
                       bw, W_row, W_col, alpha, mt, bwt);
    // 256 blocks (1/CU), each walks 8 tiles strided by 256 so the active
    // working set is a contiguous 16 MB window of x/out.
    hipLaunchKernelGGL(hbsl_main, dim3(256), dim3(512), 0, stream,
                       x, gamma, beta, bias, mt, bwt, o);
}

// Round 6
// 254.256 us; speedup vs baseline: 1.1666x; 1.0108x over previous
//
#include <hip/hip_runtime.h>

typedef __bf16 bf16x8 __attribute__((ext_vector_type(8)));
typedef __bf16 bf16x4 __attribute__((ext_vector_type(4)));
typedef float f32x4 __attribute__((ext_vector_type(4)));

#define EPS 1e-5f
#define NB 256       // grid = 256 blocks, 1/CU
#define ITERS 16     // 8-row tiles per block; 256*16*8 = 32768 rows

typedef __attribute__((address_space(3))) unsigned int lds_u32;
typedef const __attribute__((address_space(1))) unsigned int glb_u32;

// Precompute (re-runs every launch; d_ws is re-poisoned each time):
//   mt[s][c]  = alpha * M[c][s],  M = W_col @ W_row^T   (bf16, [32][32])
//   bwt[g][c][b] = bw[g][b][c]                          (bf16, [64][16][16])
__global__ __launch_bounds__(256) void hbsl_precompute(
    const float* __restrict__ bw, const float* __restrict__ W_row,
    const float* __restrict__ W_col, const float* __restrict__ alpha_p,
    __bf16* __restrict__ mt, __bf16* __restrict__ bwt)
{
    const int t = threadIdx.x;
    if (blockIdx.x == 0) {
        const float alpha = alpha_p[0];
        #pragma unroll
        for (int k = 0; k < 4; ++k) {
            int flat = t + 256 * k;
            int s = flat >> 5, c = flat & 31;
            float acc = 0.f;
            #pragma unroll 8
            for (int kk = 0; kk < 32; ++kk)
                acc += W_col[c * 32 + kk] * W_row[s * 32 + kk];
            mt[s * 32 + c] = (__bf16)(alpha * acc);
        }
    } else {
        int g = blockIdx.x - 1;
        int c = t >> 4, b = t & 15;
        bwt[g * 256 + c * 16 + b] = (__bf16)bw[g * 256 + b * 16 + c];
    }
}

// 512 threads = 8 waves, 1 block/CU, 8-ROW tiles, 4 x 32 KB buffer rotation,
// ONE __syncthreads per tile. Phase i:
//   issue DMA(i+2) -> buf[(i+2)&3]   (flies under the ENTIRE phase)
//   STATS(i+1)     on buf[(i+1)&3]   (raw fp32 -> bf16 xn in place, per-wave row)
//   MFMA(i)+store  on buf[i&3]
//   __syncthreads  (its vmcnt(0) drain = exactly when DMA(i+2) must be done)
// MFMA B rows 8..15 duplicate rows 0..7 (n&7) -> cols 8..15 of D are garbage,
// masked at store (if n<8). No inline asm, no raw barriers anywhere.
__global__ __launch_bounds__(512, 2) void hbsl_main(
    const float* __restrict__ x, const float* __restrict__ gamma,
    const float* __restrict__ beta, const float* __restrict__ bias,
    const __bf16* __restrict__ mt, const __bf16* __restrict__ bwt,
    float* __restrict__ out)
{
    __shared__ float xr[4][8192];              // 4 x 32 KB rotation = 128 KB
    const int t = threadIdx.x;
    const int lane = t & 63;
    const int wv = t >> 6;                     // 0..7: wave = LN row owner
    const int q = lane >> 4, n = lane & 15;    // MFMA lane decomposition
    const int r8 = n & 7;                      // B-operand row (duplicated)

    // ---- tile-invariant operands -> persistent registers ----
    const bf16x8 mfrag0 = *(const bf16x8*)(mt + n * 32 + q * 8);
    const bf16x8 mfrag1 = *(const bf16x8*)(mt + (16 + n) * 32 + q * 8);
    bf16x8 bwf[4];
    f32x4 biasr[8];
    #pragma unroll
    for (int p = 0; p < 4; ++p) {
        const int o0 = wv * 8 + 2 * p;
        const int gb = 31 - (o0 >> 1);
        const int g = (q >= 2) ? (2 * gb + 1) : (2 * gb);  // tile o0 : o1
        const int e = (q >= 2) ? (q - 2) * 8 : q * 8;
        bwf[p] = *(const bf16x8*)(bwt + g * 256 + (15 - n) * 16 + e);
        biasr[2 * p]     = *(const f32x4*)(bias + o0 * 16 + q * 4);
        biasr[2 * p + 1] = *(const f32x4*)(bias + o0 * 16 + 16 + q * 4);
    }
    float4 g4[4], b4[4];
    #pragma unroll
    for (int k = 0; k < 4; ++k) {
        g4[k] = *(const float4*)(gamma + k * 256 + lane * 4);
        b4[k] = *(const float4*)(beta + k * 256 + lane * 4);
    }
    bf16x8 bz;
    #pragma unroll
    for (int i = 0; i < 8; ++i) bz[i] = (__bf16)0.f;

    // DMA one 8-row tile (32 KB): wave w stages row w into its own 4 KB
    // region, linear layout (lane fan-out is lane*16 B on both sides).
    auto DMA_TILE = [&](int buf, int tile) {
        const float* src = x + (size_t)(tile * 8 + wv) * 1024 + lane * 4;
        #pragma unroll
        for (int k = 0; k < 4; ++k) {
            lds_u32* lp = (lds_u32*)(&xr[buf][wv * 1024 + k * 256]);
            __builtin_amdgcn_global_load_lds((glb_u32*)(src + k * 256), lp, 16, 0, 0);
        }
    };

    // Stats + in-place fp32->bf16 normalize of the wave's own row. xn elem c
    // is stored at c ^ (row<<3) (8-elem granule XOR) for conflict-light MFMA
    // reads; regs hold the row across the read->write (DS ops in-order/wave).
    auto STATS = [&](int buf) {
        f32x4 xv[4];
        #pragma unroll
        for (int k = 0; k < 4; ++k)
            xv[k] = *(const f32x4*)(&xr[buf][wv * 1024 + k * 256 + lane * 4]);
        float s = 0.f, ss = 0.f;
        #pragma unroll
        for (int k = 0; k < 4; ++k) {
            s  += xv[k][0] + xv[k][1] + xv[k][2] + xv[k][3];
            ss += xv[k][0]*xv[k][0] + xv[k][1]*xv[k][1]
                + xv[k][2]*xv[k][2] + xv[k][3]*xv[k][3];
        }
        #pragma unroll
        for (int m = 1; m < 64; m <<= 1) {
            s  += __shfl_xor(s, m, 64);
            ss += __shfl_xor(ss, m, 64);
        }
        const float mu = s * (1.f / 1024.f);
        const float rs = rsqrtf(ss * (1.f / 1024.f) - mu * mu + EPS);
        __bf16* xnb = (__bf16*)(&xr[buf][0]);
        #pragma unroll
        for (int k = 0; k < 4; ++k) {
            bf16x4 w;
            w[0] = (__bf16)((xv[k][0] - mu) * rs * g4[k].x + b4[k].x);
            w[1] = (__bf16)((xv[k][1] - mu) * rs * g4[k].y + b4[k].y);
            w[2] = (__bf16)((xv[k][2] - mu) * rs * g4[k].z + b4[k].z);
            w[3] = (__bf16)((xv[k][3] - mu) * rs * g4[k].w + b4[k].w);
            const int c = (k * 256 + lane * 4) ^ (wv << 3);
            *(bf16x4*)(&xnb[wv * 2048 + c]) = w;     // within own 4 KB region
        }
    };

    auto MFMA_PHASE = [&](int buf, int tile) {
        const __bf16* xnb = (const __bf16*)(&xr[buf][0]);
        float* orow = out + (size_t)(tile * 8 + n) * 1024;   // valid for n<8
        #pragma unroll
        for (int p = 0; p < 4; ++p) {
            const int o0 = wv * 8 + 2 * p;    // even out-tile; o1 = o0+1
            const int rw = o0 >> 1;           // monarch window cols [32rw,+32)
            const int gp = 31 - rw;           // block-diag window
            bf16x8 az = *(const bf16x8*)(&xnb[r8 * 2048 + ((rw * 32 + q * 8) ^ (r8 << 3))]);
            bf16x8 ay = *(const bf16x8*)(&xnb[r8 * 2048 + ((gp * 32 + q * 8) ^ (r8 << 3))]);
            bf16x8 a0 = (q >= 2) ? bwf[p] : bz;   // tile o0: k in [16,32)
            bf16x8 a1 = (q <  2) ? bwf[p] : bz;   // tile o1: k in [0,16)
            f32x4 d0 = __builtin_amdgcn_mfma_f32_16x16x32_bf16(mfrag0, az, biasr[2*p], 0, 0, 0);
            f32x4 d1 = __builtin_amdgcn_mfma_f32_16x16x32_bf16(mfrag1, az, biasr[2*p+1], 0, 0, 0);
            d0 = __builtin_amdgcn_mfma_f32_16x16x32_bf16(a0, ay, d0, 0, 0, 0);
            d1 = __builtin_amdgcn_mfma_f32_16x16x32_bf16(a1, ay, d1, 0, 0, 0);
            if (n < 8) {                      // rows 8..15 are duplicates
                float* op = orow + o0 * 16 + q * 4;
                *(f32x4*)op        = d0;
                *(f32x4*)(op + 16) = d1;
            }
        }
    };

    const int tb = blockIdx.x;    // tile for iteration i is tb + NB*i

    // ---- prologue ----
    DMA_TILE(0, tb);
    DMA_TILE(1, tb + NB);
    __syncthreads();              // tiles 0,1 staged
    STATS(0);
    __syncthreads();              // xn(0) visible block-wide

    #pragma unroll
    for (int i = 0; i < ITERS; ++i) {
        if (i + 2 < ITERS) DMA_TILE((i + 2) & 3, tb + NB * (i + 2));
        if (i + 1 < ITERS) STATS((i + 1) & 3);
        MFMA_PHASE(i & 3, tb + NB * i);
        if (i + 1 < ITERS) __syncthreads();   // drains DMA(i+2) after full phase
    }
}

extern "C" void kernel_launch(void* const* d_in, const int* in_sizes, int n_in,
                              void* d_out, int out_size, void* d_ws, size_t ws_size,
                              hipStream_t stream) {
    const float* x      = (const float*)d_in[0];
    const float* gamma  = (const float*)d_in[1];
    const float* beta   = (const float*)d_in[2];
    const float* bw     = (const float*)d_in[3];
    const float* W_row  = (const float*)d_in[4];
    const float* W_col  = (const float*)d_in[5];
    const float* alpha  = (const float*)d_in[6];
    const float* bias   = (const float*)d_in[7];
    float* o = (float*)d_out;

    __bf16* mt  = (__bf16*)d_ws;                       // 32*32*2   = 2048 B
    __bf16* bwt = (__bf16*)((char*)d_ws + 2048);       // 64*256*2  = 32768 B

    hipLaunchKernelGGL(hbsl_precompute, dim3(65), dim3(256), 0, stream,
                       bw, W_row, W_col, alpha, mt, bwt);
    hipLaunchKernelGGL(hbsl_main, dim3(NB), dim3(512), 0, stream,
                       x, gamma, beta, bias, mt, bwt, o);
}